// Round 7
// baseline (74.793 us; speedup 1.0000x reference)
//
#include <hip/hip_runtime.h>

// YOLO layer decode: (B, nA*(nC+5), g, g) f32 -> (B, nA*g*g, nC+5) f32
// B=64, nA=3, nC=80, g=52, stride = img_dim/g = 8.
//
// R7 = R5 structure (persistent 4-row blocks, dbuf LDS, raw lgkmcnt barrier)
// with the cache policy FLIPPED: nontemporal LOADS (input is single-use per
// replay -> don't allocate in L3), normal STORES (let the 176.5 MB output
// stay dirty-resident in the 256 MB Infinity Cache across graph replays so
// HBM write traffic collapses). R4/R6 showed nt-stores don't stop
// write-allocate; this is the other side of that coin.

#define G_        52
#define S_        2704                 // 52*52
#define NA_       3
#define C_        85                   // nC + 5
#define B_        64
#define ROW_WORDS (G_ * C_)            // 4420 floats per row-tile
#define ITEMS     (ROW_WORDS / 4)      // 1105 float4 items per row
#define ROWS_PB   4                    // rows per block; 13 blocks * 4 = 52
#define LOG2E_    1.44269504088896340736f

typedef float f32x4 __attribute__((ext_vector_type(4)));

__device__ __forceinline__ float fast_sigmoid(float v) {
    // 1/(1+e^-v) = rcp(1 + 2^(-v*log2e)); v_exp_f32 + v_rcp_f32
    float e = __builtin_amdgcn_exp2f(-LOG2E_ * v);
    return __builtin_amdgcn_rcpf(1.0f + e);
}

__global__ __launch_bounds__(256) void yolo_decode_kernel(
    const float* __restrict__ x,
    const int*   __restrict__ img_dim_p,
    float*       __restrict__ out)
{
    __shared__ float lds[2][ROW_WORDS];   // 35360 B -> 4 blocks/CU

    const int rb  = blockIdx.x;           // 0..12
    const int a   = blockIdx.y;
    const int b   = blockIdx.z;
    const int tid = threadIdx.x;
    const int row0 = rb * ROWS_PB;

    // img_dim may arrive as int32 or float32 bits; disambiguate.
    int   bits = img_dim_p[0];
    float img  = (bits > 0 && bits < (1 << 20)) ? (float)bits
                                                : __int_as_float(bits);
    const float stride = img / (float)G_;   // 8.0

    const float aw = (a == 0) ? 10.0f : (a == 1) ? 16.0f : 33.0f;
    const float ah = (a == 0) ? 13.0f : (a == 1) ? 30.0f : 23.0f;

    const float* inb   = x   + (size_t)(b * NA_ + a) * (size_t)(C_ * S_);
    float*       outb0 = out + (size_t)(b * NA_ + a) * (size_t)S_ * C_;

    // Row-invariant per-thread decomposition: item q -> (channel c, quad sq)
    int c_[5], sq_[5];
    #pragma unroll
    for (int i = 0; i < 5; ++i) {
        const int q = tid + 256 * i;
        c_[i]  = q / 13;                  // magic-mul div
        sq_[i] = q - 13 * c_[i];
    }
    const bool act4 = (tid < ITEMS - 1024);   // 81 threads active in slot 4

    f32x4 regs[5];

    // prologue: load row0 (nontemporal: input is single-use, keep L3 for out)
    #pragma unroll
    for (int i = 0; i < 5; ++i)
        if (i < 4 || act4)
            regs[i] = __builtin_nontemporal_load(
                reinterpret_cast<const f32x4*>(
                    inb + (size_t)c_[i] * S_ + row0 * G_ + 4 * sq_[i]));

    for (int r = 0; r < ROWS_PB; ++r) {
        const int row  = row0 + r;
        float*    buf  = lds[r & 1];
        const float rowf = (float)row;    // grid_y for this whole row

        // ---- math + transpose-scatter into LDS (consumes regs) ----
        #pragma unroll
        for (int i = 0; i < 5; ++i) {
            if (i < 4 || act4) {
                const int c  = c_[i];     // near-wave-uniform
                const int sq = sq_[i];
                f32x4 v = regs[i];
                if (c >= 4) {
                    #pragma unroll
                    for (int m = 0; m < 4; ++m) v[m] = fast_sigmoid(v[m]);
                } else if (c == 0) {
                    #pragma unroll
                    for (int m = 0; m < 4; ++m)
                        v[m] = (fast_sigmoid(v[m]) + (float)(4 * sq + m)) * stride;
                } else if (c == 1) {
                    #pragma unroll
                    for (int m = 0; m < 4; ++m)
                        v[m] = (fast_sigmoid(v[m]) + rowf) * stride;
                } else if (c == 2) {
                    #pragma unroll
                    for (int m = 0; m < 4; ++m)
                        v[m] = __builtin_amdgcn_exp2f(LOG2E_ * v[m]) * aw;
                } else {  // c == 3
                    #pragma unroll
                    for (int m = 0; m < 4; ++m)
                        v[m] = __builtin_amdgcn_exp2f(LOG2E_ * v[m]) * ah;
                }
                const int base = 4 * sq * C_ + c;
                buf[base         ] = v[0];
                buf[base +     C_] = v[1];
                buf[base + 2 * C_] = v[2];
                buf[base + 3 * C_] = v[3];
            }
        }

        // ---- prefetch row r+1 (stays in flight across the raw barrier) ----
        if (r + 1 < ROWS_PB) {
            #pragma unroll
            for (int i = 0; i < 5; ++i)
                if (i < 4 || act4)
                    regs[i] = __builtin_nontemporal_load(
                        reinterpret_cast<const f32x4*>(
                            inb + (size_t)c_[i] * S_ + (row + 1) * G_ + 4 * sq_[i]));
        }

        // ---- barrier: order LDS only; do NOT drain vmcnt (keep prefetch
        //      loads + prior stores in flight). All waves execute this. ----
        asm volatile("s_waitcnt lgkmcnt(0)" ::: "memory");
        __builtin_amdgcn_s_barrier();

        // ---- store phase: linear ds_read_b128 + coalesced NORMAL stores
        //      (allocate in L3; output stays dirty-resident across replays) ----
        float* outr = outb0 + (size_t)row * ROW_WORDS;
        #pragma unroll
        for (int i = 0; i < 5; ++i) {
            if (i < 4 || act4) {
                const int q = tid + 256 * i;
                const f32x4 v = *reinterpret_cast<const f32x4*>(&buf[4 * q]);
                *reinterpret_cast<f32x4*>(outr + 4 * q) = v;
            }
        }
        // next iteration's ds_write targets the other buffer; its WAR on this
        // buffer is protected by the next iteration's lgkmcnt(0)+barrier.
    }
}

extern "C" void kernel_launch(void* const* d_in, const int* in_sizes, int n_in,
                              void* d_out, int out_size, void* d_ws, size_t ws_size,
                              hipStream_t stream)
{
    const float* x   = (const float*)d_in[0];
    const int*   img = (const int*)d_in[1];
    float*       out = (float*)d_out;

    dim3 block(256);
    yolo_decode_kernel<<<dim3(13, NA_, B_), block, 0, stream>>>(x, img, out);
}

// Round 8
// 62.751 us; speedup vs baseline: 1.1919x; 1.1919x over previous
//
#include <hip/hip_runtime.h>

// YOLO layer decode: (B, nA*(nC+5), g, g) f32 -> (B, nA*g*g, nC+5) f32
// B=64, nA=3, nC=80, g=52, stride = img_dim/g = 8.
//
// R8 = revert to R5 (best measured: 63.35 us, 88.5% of copy ceiling).
// Cache-policy map (measured): normal loads + NT stores is the optimum;
// NT loads kill the ~70 MB cross-replay L3 input residency (R7: +11.4 us).
// Structure: persistent 4-row blocks, double-buffered LDS (one g=52 row per
// buffer), register prefetch of row r+1 before a raw lgkmcnt(0)-only
// s_barrier so global loads stay in flight across the barrier.

#define G_        52
#define S_        2704                 // 52*52
#define NA_       3
#define C_        85                   // nC + 5
#define B_        64
#define ROW_WORDS (G_ * C_)            // 4420 floats per row-tile
#define ITEMS     (ROW_WORDS / 4)      // 1105 float4 items per row
#define ROWS_PB   4                    // rows per block; 13 blocks * 4 = 52
#define LOG2E_    1.44269504088896340736f

typedef float f32x4 __attribute__((ext_vector_type(4)));

__device__ __forceinline__ float fast_sigmoid(float v) {
    // 1/(1+e^-v) = rcp(1 + 2^(-v*log2e)); v_exp_f32 + v_rcp_f32
    float e = __builtin_amdgcn_exp2f(-LOG2E_ * v);
    return __builtin_amdgcn_rcpf(1.0f + e);
}

__global__ __launch_bounds__(256) void yolo_decode_kernel(
    const float* __restrict__ x,
    const int*   __restrict__ img_dim_p,
    float*       __restrict__ out)
{
    __shared__ float lds[2][ROW_WORDS];   // 35360 B -> 4 blocks/CU

    const int rb  = blockIdx.x;           // 0..12
    const int a   = blockIdx.y;
    const int b   = blockIdx.z;
    const int tid = threadIdx.x;
    const int row0 = rb * ROWS_PB;

    // img_dim may arrive as int32 or float32 bits; disambiguate.
    int   bits = img_dim_p[0];
    float img  = (bits > 0 && bits < (1 << 20)) ? (float)bits
                                                : __int_as_float(bits);
    const float stride = img / (float)G_;   // 8.0

    const float aw = (a == 0) ? 10.0f : (a == 1) ? 16.0f : 33.0f;
    const float ah = (a == 0) ? 13.0f : (a == 1) ? 30.0f : 23.0f;

    const float* inb   = x   + (size_t)(b * NA_ + a) * (size_t)(C_ * S_);
    float*       outb0 = out + (size_t)(b * NA_ + a) * (size_t)S_ * C_;

    // Row-invariant per-thread decomposition: item q -> (channel c, quad sq)
    int c_[5], sq_[5];
    #pragma unroll
    for (int i = 0; i < 5; ++i) {
        const int q = tid + 256 * i;
        c_[i]  = q / 13;                  // magic-mul div
        sq_[i] = q - 13 * c_[i];
    }
    const bool act4 = (tid < ITEMS - 1024);   // 81 threads active in slot 4

    f32x4 regs[5];

    // prologue: load row0 (normal loads — input stays L3-resident across replays)
    #pragma unroll
    for (int i = 0; i < 5; ++i)
        if (i < 4 || act4)
            regs[i] = *reinterpret_cast<const f32x4*>(
                inb + (size_t)c_[i] * S_ + row0 * G_ + 4 * sq_[i]);

    for (int r = 0; r < ROWS_PB; ++r) {
        const int row  = row0 + r;
        float*    buf  = lds[r & 1];
        const float rowf = (float)row;    // grid_y for this whole row

        // ---- math + transpose-scatter into LDS (consumes regs) ----
        #pragma unroll
        for (int i = 0; i < 5; ++i) {
            if (i < 4 || act4) {
                const int c  = c_[i];     // near-wave-uniform
                const int sq = sq_[i];
                f32x4 v = regs[i];
                if (c >= 4) {
                    #pragma unroll
                    for (int m = 0; m < 4; ++m) v[m] = fast_sigmoid(v[m]);
                } else if (c == 0) {
                    #pragma unroll
                    for (int m = 0; m < 4; ++m)
                        v[m] = (fast_sigmoid(v[m]) + (float)(4 * sq + m)) * stride;
                } else if (c == 1) {
                    #pragma unroll
                    for (int m = 0; m < 4; ++m)
                        v[m] = (fast_sigmoid(v[m]) + rowf) * stride;
                } else if (c == 2) {
                    #pragma unroll
                    for (int m = 0; m < 4; ++m)
                        v[m] = __builtin_amdgcn_exp2f(LOG2E_ * v[m]) * aw;
                } else {  // c == 3
                    #pragma unroll
                    for (int m = 0; m < 4; ++m)
                        v[m] = __builtin_amdgcn_exp2f(LOG2E_ * v[m]) * ah;
                }
                const int base = 4 * sq * C_ + c;
                buf[base         ] = v[0];
                buf[base +     C_] = v[1];
                buf[base + 2 * C_] = v[2];
                buf[base + 3 * C_] = v[3];
            }
        }

        // ---- prefetch row r+1 (stays in flight across the raw barrier) ----
        if (r + 1 < ROWS_PB) {
            #pragma unroll
            for (int i = 0; i < 5; ++i)
                if (i < 4 || act4)
                    regs[i] = *reinterpret_cast<const f32x4*>(
                        inb + (size_t)c_[i] * S_ + (row + 1) * G_ + 4 * sq_[i]);
        }

        // ---- barrier: order LDS only; do NOT drain vmcnt (keep prefetch
        //      loads + prior stores in flight). All waves execute this. ----
        asm volatile("s_waitcnt lgkmcnt(0)" ::: "memory");
        __builtin_amdgcn_s_barrier();

        // ---- store phase: linear ds_read_b128 + coalesced NT stores ----
        float* outr = outb0 + (size_t)row * ROW_WORDS;
        #pragma unroll
        for (int i = 0; i < 5; ++i) {
            if (i < 4 || act4) {
                const int q = tid + 256 * i;
                const f32x4 v = *reinterpret_cast<const f32x4*>(&buf[4 * q]);
                __builtin_nontemporal_store(v, reinterpret_cast<f32x4*>(outr + 4 * q));
            }
        }
        // next iteration's ds_write targets the other buffer; its WAR on this
        // buffer is protected by the next iteration's lgkmcnt(0)+barrier.
    }
}

extern "C" void kernel_launch(void* const* d_in, const int* in_sizes, int n_in,
                              void* d_out, int out_size, void* d_ws, size_t ws_size,
                              hipStream_t stream)
{
    const float* x   = (const float*)d_in[0];
    const int*   img = (const int*)d_in[1];
    float*       out = (float*)d_out;

    dim3 block(256);
    yolo_decode_kernel<<<dim3(13, NA_, B_), block, 0, stream>>>(x, img, out);
}